// Round 1
// baseline (198.708 us; speedup 1.0000x reference)
//
#include <hip/hip_runtime.h>
#include <hip/hip_bf16.h>

#define H_DIM 768
#define S_LEN 128
#define BK 64

typedef __attribute__((ext_vector_type(8))) short short8;
typedef __attribute__((ext_vector_type(4))) float f32x4;

__device__ __forceinline__ void gload_lds16(const void* g, void* l) {
  __builtin_amdgcn_global_load_lds(
      (const __attribute__((address_space(1))) unsigned int*)g,
      (__attribute__((address_space(3))) unsigned int*)l, 16, 0, 0);
}

// ---------------- Kernel 1: per-token L2 normalize, fp32 -> bf16 ----------------
__global__ __launch_bounds__(256) void norm_bf16_kernel(
    const float* __restrict__ x, unsigned short* __restrict__ xn) {
  const int tok = blockIdx.x;
  const float* row = x + (size_t)tok * H_DIM;
  const int tid = threadIdx.x;
  float4 v = make_float4(0.f, 0.f, 0.f, 0.f);
  float ss = 0.f;
  if (tid < 192) {  // 192 * 4 = 768 floats
    v = reinterpret_cast<const float4*>(row)[tid];
    ss = v.x * v.x + v.y * v.y + v.z * v.z + v.w * v.w;
  }
#pragma unroll
  for (int o = 32; o > 0; o >>= 1) ss += __shfl_down(ss, o);
  __shared__ float ws[4];
  if ((tid & 63) == 0) ws[tid >> 6] = ss;
  __syncthreads();
  const float tot = ws[0] + ws[1] + ws[2] + ws[3];
  const float scale = 1.0f / sqrtf(tot);  // norms ~27.7, far from EPS=1e-8
  if (tid < 192) {
    union { ushort4 u; __hip_bfloat16 h[4]; } o;
    o.h[0] = __float2bfloat16(v.x * scale);
    o.h[1] = __float2bfloat16(v.y * scale);
    o.h[2] = __float2bfloat16(v.z * scale);
    o.h[3] = __float2bfloat16(v.w * scale);
    reinterpret_cast<ushort4*>(xn + (size_t)tok * H_DIM)[tid] = o.u;
  }
}

// ---------------- Kernel 2: per-(a,b) 128x128 sim tile + masked max/mean ----------------
// 4 waves: wave w at (wm,wn)=(w>>1,w&1) owns a 64x64 quadrant (4x4 of 16x16 frags).
// LDS staging is linear (global_load_lds requirement); the 16B chunk index within
// each row is XOR-swizzled on the GLOBAL source and on the ds_read so the MFMA
// fragment reads (row-stride 128B) spread across banks (2-way = free).
__global__ __launch_bounds__(256) void rwmd_kernel(
    const unsigned short* __restrict__ xn1, const unsigned short* __restrict__ xn2,
    const int* __restrict__ mask1, const int* __restrict__ mask2,
    float* __restrict__ out) {
  __shared__ __align__(16) unsigned char smem[S_LEN * 129 * 4];  // 66048 B
  unsigned short* Al = (unsigned short*)smem;                    // [128][64] bf16
  unsigned short* Bl = (unsigned short*)(smem + 16384);          // [128][64] bf16
  float* sim = (float*)smem;                                     // [128][129] f32 (reuse)
  __shared__ int m1s[S_LEN], m2s[S_LEN];
  __shared__ float rmax[S_LEN], cmax[S_LEN];

  const int a = blockIdx.x >> 6;
  const int b = blockIdx.x & 63;
  const int tid = threadIdx.x;
  const int lane = tid & 63;
  const int w = tid >> 6;
  const int wm = w >> 1, wn = w & 1;

  const unsigned short* A0 = xn1 + (size_t)a * (S_LEN * H_DIM);
  const unsigned short* B0 = xn2 + (size_t)b * (S_LEN * H_DIM);

  f32x4 acc[4][4];
#pragma unroll
  for (int i = 0; i < 4; ++i)
#pragma unroll
    for (int j = 0; j < 4; ++j) acc[i][j] = (f32x4){0.f, 0.f, 0.f, 0.f};

  for (int k0 = 0; k0 < H_DIM; k0 += BK) {
    __syncthreads();  // previous compute done before DMA overwrites LDS
#pragma unroll
    for (int c = 0; c < 4; ++c) {
      const int s = (w * 4 + c) * 64 + lane;  // 16B-chunk slot 0..1023
      const int row = s >> 3;                 // 8 chunks (128B) per row
      const int cb = (s & 7) ^ (row & 7);     // inverse-swizzled source chunk
      gload_lds16(A0 + (size_t)row * H_DIM + k0 + cb * 8, Al + s * 8);
      gload_lds16(B0 + (size_t)row * H_DIM + k0 + cb * 8, Bl + s * 8);
    }
    __syncthreads();  // compiler drains vmcnt(0) before barrier
    const int g = lane >> 4;
    const int rl = lane & 15;
#pragma unroll
    for (int kf = 0; kf < 2; ++kf) {
      short8 av[4], bv[4];
#pragma unroll
      for (int i = 0; i < 4; ++i) {
        const int r = wm * 64 + i * 16 + rl;
        const int slot = (kf * 4 + g) ^ (r & 7);  // swizzled read
        av[i] = *reinterpret_cast<const short8*>(&Al[r * 64 + slot * 8]);
      }
#pragma unroll
      for (int j = 0; j < 4; ++j) {
        const int r = wn * 64 + j * 16 + rl;
        const int slot = (kf * 4 + g) ^ (r & 7);
        bv[j] = *reinterpret_cast<const short8*>(&Bl[r * 64 + slot * 8]);
      }
#pragma unroll
      for (int i = 0; i < 4; ++i)
#pragma unroll
        for (int j = 0; j < 4; ++j)
          acc[i][j] = __builtin_amdgcn_mfma_f32_16x16x32_bf16(av[i], bv[j], acc[i][j], 0, 0, 0);
    }
  }

  __syncthreads();  // all LDS reads done before sim-tile overwrite
  if (tid < 128) m1s[tid] = mask1[a * S_LEN + tid];
  else           m2s[tid - 128] = mask2[b * S_LEN + (tid - 128)];

  // C/D layout (m89-verified): col = lane&15, row = (lane>>4)*4 + reg
  {
    const int rl = lane & 15, g = lane >> 4;
#pragma unroll
    for (int i = 0; i < 4; ++i) {
      const int rb = wm * 64 + i * 16 + g * 4;
#pragma unroll
      for (int j = 0; j < 4; ++j) {
        const int col = wn * 64 + j * 16 + rl;
#pragma unroll
        for (int r = 0; r < 4; ++r)
          sim[(rb + r) * 129 + col] = acc[i][j][r];
      }
    }
  }
  __syncthreads();

  // masked row-max (threads 0..127) / col-max (threads 128..255)
  // stride 129 dwords == 1 mod 32 -> conflict-free scans
  float mv = -INFINITY;
  if (tid < 128) {
    for (int j = 0; j < 128; ++j)
      mv = fmaxf(mv, m2s[j] ? sim[tid * 129 + j] : -INFINITY);
    rmax[tid] = mv;
  } else {
    const int c = tid - 128;
    for (int i = 0; i < 128; ++i)
      mv = fmaxf(mv, m1s[i] ? sim[i * 129 + c] : -INFINITY);
    cmax[c] = mv;
  }
  __syncthreads();

  if (w == 0) {
    float v1 = 0.f, c1 = 0.f, v2 = 0.f, c2 = 0.f;
    if (m1s[lane])      { v1 += rmax[lane];      c1 += 1.f; }
    if (m1s[lane + 64]) { v1 += rmax[lane + 64]; c1 += 1.f; }
    if (m2s[lane])      { v2 += cmax[lane];      c2 += 1.f; }
    if (m2s[lane + 64]) { v2 += cmax[lane + 64]; c2 += 1.f; }
#pragma unroll
    for (int o = 32; o > 0; o >>= 1) {
      v1 += __shfl_down(v1, o); c1 += __shfl_down(c1, o);
      v2 += __shfl_down(v2, o); c2 += __shfl_down(c2, o);
    }
    if (lane == 0) out[blockIdx.x] = 0.5f * (v1 / c1 + v2 / c2);
  }
}

extern "C" void kernel_launch(void* const* d_in, const int* in_sizes, int n_in,
                              void* d_out, int out_size, void* d_ws, size_t ws_size,
                              hipStream_t stream) {
  const float* x1 = (const float*)d_in[0];
  const int* mask1 = (const int*)d_in[1];
  const float* x2 = (const float*)d_in[2];
  const int* mask2 = (const int*)d_in[3];
  float* out = (float*)d_out;

  unsigned short* xn1 = (unsigned short*)d_ws;                       // 64*128*768 bf16
  unsigned short* xn2 = xn1 + (size_t)64 * 128 * 768;                // 12.6 MB each

  norm_bf16_kernel<<<64 * 128, 256, 0, stream>>>(x1, xn1);
  norm_bf16_kernel<<<64 * 128, 256, 0, stream>>>(x2, xn2);
  rwmd_kernel<<<64 * 64, 256, 0, stream>>>(xn1, xn2, mask1, mask2, out);
}

// Round 2
// 123.198 us; speedup vs baseline: 1.6129x; 1.6129x over previous
//
#include <hip/hip_runtime.h>
#include <hip/hip_bf16.h>

#define H_DIM 768
#define S_LEN 128
#define BK 64

typedef __attribute__((ext_vector_type(8))) short short8;
typedef __attribute__((ext_vector_type(4))) float f32x4;

__device__ __forceinline__ void gload_lds16(const void* g, void* l) {
  __builtin_amdgcn_global_load_lds(
      (const __attribute__((address_space(1))) unsigned int*)g,
      (__attribute__((address_space(3))) unsigned int*)l, 16, 0, 0);
}

// ---------------- Kernel 1: per-token L2 normalize, fp32 -> bf16 ----------------
__global__ __launch_bounds__(256) void norm_bf16_kernel(
    const float* __restrict__ x, unsigned short* __restrict__ xn) {
  const int tok = blockIdx.x;
  const float* row = x + (size_t)tok * H_DIM;
  const int tid = threadIdx.x;
  float4 v = make_float4(0.f, 0.f, 0.f, 0.f);
  float ss = 0.f;
  if (tid < 192) {  // 192 * 4 = 768 floats
    v = reinterpret_cast<const float4*>(row)[tid];
    ss = v.x * v.x + v.y * v.y + v.z * v.z + v.w * v.w;
  }
#pragma unroll
  for (int o = 32; o > 0; o >>= 1) ss += __shfl_down(ss, o);
  __shared__ float ws[4];
  if ((tid & 63) == 0) ws[tid >> 6] = ss;
  __syncthreads();
  const float tot = ws[0] + ws[1] + ws[2] + ws[3];
  const float scale = 1.0f / sqrtf(tot);  // norms ~27.7, far from EPS=1e-8
  if (tid < 192) {
    union { ushort4 u; __hip_bfloat16 h[4]; } o;
    o.h[0] = __float2bfloat16(v.x * scale);
    o.h[1] = __float2bfloat16(v.y * scale);
    o.h[2] = __float2bfloat16(v.z * scale);
    o.h[3] = __float2bfloat16(v.w * scale);
    reinterpret_cast<ushort4*>(xn + (size_t)tok * H_DIM)[tid] = o.u;
  }
}

// ---------------- Kernel 2: one block = pair-batch (a, {b0,b1}), 128x256 tile ----------------
// 8 waves in 2x4 grid: wave w -> (wm,wn)=(w>>2, w&3); wave tile = rows wm*64..+64
// (x1 tokens), cols wn*64..+64 of 256 (x2 tokens of b0|b1; b = wn>>1).
// Masked row/col maxes are computed IN REGISTERS from the MFMA accumulator
// (C/D layout m89: col=lane&15, row=(lane>>4)*4+reg), reduced via shfl_xor;
// only 4x128 + 2x256 f32 partials touch LDS. No sim tile, no serial scans.
__global__ __launch_bounds__(512, 4) void rwmd_kernel(
    const unsigned short* __restrict__ xn1, const unsigned short* __restrict__ xn2,
    const int* __restrict__ mask1, const int* __restrict__ mask2,
    float* __restrict__ out) {
  __shared__ __align__(16) unsigned short Al[S_LEN * BK];      // 16 KB  [128][64]
  __shared__ __align__(16) unsigned short Bl[2 * S_LEN * BK];  // 32 KB  [256][64]
  __shared__ int m1s[S_LEN], m2s[2 * S_LEN];
  __shared__ float rpart[4][S_LEN];      // per-wn row partial max
  __shared__ float cpart[2][2 * S_LEN];  // per-wm col partial max

  const int a = blockIdx.x >> 5;        // 64 a's
  const int bp = blockIdx.x & 31;       // 32 b-pairs
  const int b0 = bp * 2;
  const int tid = threadIdx.x;
  const int lane = tid & 63;
  const int w = tid >> 6;
  const int wm = w >> 2, wn = w & 3;
  const int g = lane >> 4, rl = lane & 15;

  const unsigned short* A0 = xn1 + (size_t)a * (S_LEN * H_DIM);
  const unsigned short* B0 = xn2 + (size_t)b0 * (S_LEN * H_DIM);  // b0,b1 contiguous: 256 rows

  // masks (contiguous across b0,b1 as well)
  if (tid < S_LEN) m1s[tid] = mask1[a * S_LEN + tid];
  else if (tid < 3 * S_LEN) m2s[tid - S_LEN] = mask2[b0 * S_LEN + (tid - S_LEN)];

  f32x4 acc[4][4];
#pragma unroll
  for (int i = 0; i < 4; ++i)
#pragma unroll
    for (int j = 0; j < 4; ++j) acc[i][j] = (f32x4){0.f, 0.f, 0.f, 0.f};

  for (int k0 = 0; k0 < H_DIM; k0 += BK) {
    __syncthreads();  // previous compute done before DMA overwrites LDS
    // A: 1024 16B-chunks, B: 2048 chunks; 6 per thread. Linear LDS dest,
    // inverse-swizzled global source (rule 21).
#pragma unroll
    for (int t = 0; t < 2; ++t) {
      const int s = t * 512 + tid;
      const int row = s >> 3;
      const int cb = (s & 7) ^ (row & 7);
      gload_lds16(A0 + (size_t)row * H_DIM + k0 + cb * 8, Al + s * 8);
    }
#pragma unroll
    for (int t = 0; t < 4; ++t) {
      const int s = t * 512 + tid;
      const int row = s >> 3;  // 0..255
      const int cb = (s & 7) ^ (row & 7);
      gload_lds16(B0 + (size_t)row * H_DIM + k0 + cb * 8, Bl + s * 8);
    }
    __syncthreads();  // compiler drains vmcnt(0) before barrier
#pragma unroll
    for (int kf = 0; kf < 2; ++kf) {
      short8 av[4], bv[4];
#pragma unroll
      for (int i = 0; i < 4; ++i) {
        const int r = wm * 64 + i * 16 + rl;
        const int slot = (kf * 4 + g) ^ (r & 7);  // swizzled read
        av[i] = *reinterpret_cast<const short8*>(&Al[r * BK + slot * 8]);
      }
#pragma unroll
      for (int j = 0; j < 4; ++j) {
        const int r = wn * 64 + j * 16 + rl;  // 0..255
        const int slot = (kf * 4 + g) ^ (r & 7);
        bv[j] = *reinterpret_cast<const short8*>(&Bl[r * BK + slot * 8]);
      }
#pragma unroll
      for (int i = 0; i < 4; ++i)
#pragma unroll
        for (int j = 0; j < 4; ++j)
          acc[i][j] = __builtin_amdgcn_mfma_f32_16x16x32_bf16(av[i], bv[j], acc[i][j], 0, 0, 0);
    }
  }

  // ---- in-register masked reductions ----
  // acc[i][j][r]: row = wm*64 + i*16 + g*4 + r, col = wn*64 + j*16 + rl
  // row-partial max over this wave's 64 cols:
#pragma unroll
  for (int i = 0; i < 4; ++i) {
#pragma unroll
    for (int r = 0; r < 4; ++r) {
      float pm = -INFINITY;
#pragma unroll
      for (int j = 0; j < 4; ++j) {
        const int col = wn * 64 + j * 16 + rl;
        pm = fmaxf(pm, m2s[col] ? acc[i][j][r] : -INFINITY);
      }
#pragma unroll
      for (int o = 1; o < 16; o <<= 1) pm = fmaxf(pm, __shfl_xor(pm, o));
      if (rl == 0) rpart[wn][wm * 64 + i * 16 + g * 4 + r] = pm;
    }
  }
  // col-partial max over this wave's 64 rows:
#pragma unroll
  for (int j = 0; j < 4; ++j) {
    float cm = -INFINITY;
#pragma unroll
    for (int i = 0; i < 4; ++i)
#pragma unroll
      for (int r = 0; r < 4; ++r) {
        const int row = wm * 64 + i * 16 + g * 4 + r;
        cm = fmaxf(cm, m1s[row] ? acc[i][j][r] : -INFINITY);
      }
    cm = fmaxf(cm, __shfl_xor(cm, 16));
    cm = fmaxf(cm, __shfl_xor(cm, 32));
    if (g == 0) cpart[wm][wn * 64 + j * 16 + rl] = cm;
  }
  __syncthreads();

  // ---- final masked means: wave 0 -> pair b0, wave 1 -> pair b1 ----
  if (w < 2) {
    float v1 = 0.f, c1 = 0.f, v2 = 0.f, c2 = 0.f;
#pragma unroll
    for (int t = 0; t < 2; ++t) {
      const int r = lane + t * 64;
      if (m1s[r]) { v1 += fmaxf(rpart[2 * w][r], rpart[2 * w + 1][r]); c1 += 1.f; }
      const int c = w * 128 + lane + t * 64;
      if (m2s[c]) { v2 += fmaxf(cpart[0][c], cpart[1][c]); c2 += 1.f; }
    }
#pragma unroll
    for (int o = 32; o > 0; o >>= 1) {
      v1 += __shfl_down(v1, o); c1 += __shfl_down(c1, o);
      v2 += __shfl_down(v2, o); c2 += __shfl_down(c2, o);
    }
    if (lane == 0) out[a * 64 + b0 + w] = 0.5f * (v1 / c1 + v2 / c2);
  }
}

extern "C" void kernel_launch(void* const* d_in, const int* in_sizes, int n_in,
                              void* d_out, int out_size, void* d_ws, size_t ws_size,
                              hipStream_t stream) {
  const float* x1 = (const float*)d_in[0];
  const int* mask1 = (const int*)d_in[1];
  const float* x2 = (const float*)d_in[2];
  const int* mask2 = (const int*)d_in[3];
  float* out = (float*)d_out;

  unsigned short* xn1 = (unsigned short*)d_ws;         // 64*128*768 bf16
  unsigned short* xn2 = xn1 + (size_t)64 * 128 * 768;  // 12.6 MB each

  norm_bf16_kernel<<<64 * 128, 256, 0, stream>>>(x1, xn1);
  norm_bf16_kernel<<<64 * 128, 256, 0, stream>>>(x2, xn2);
  rwmd_kernel<<<64 * 32, 512, 0, stream>>>(xn1, xn2, mask1, mask2, out);
}